// Round 21
// baseline (161.265 us; speedup 1.0000x reference)
//
#include <hip/hip_runtime.h>

typedef short short8 __attribute__((ext_vector_type(8)));
typedef short short4v __attribute__((ext_vector_type(4)));
typedef float f32x4 __attribute__((ext_vector_type(4)));
typedef float f32x16 __attribute__((ext_vector_type(16)));
typedef unsigned uint2v __attribute__((ext_vector_type(2)));

typedef __attribute__((address_space(1))) void gvoid;
typedef __attribute__((address_space(3))) void lvoid;

#define DEV static __device__ __forceinline__

constexpr int Dm = 512;   // model dim
constexpr int Sm = 4096;  // seq len
constexpr int Hh = 8;     // heads
constexpr long NTe = (long)2 * Sm * Dm;  // elements per [B,S,D] tensor

// 0.125 (=1/sqrt(64)) * log2(e): folded into Q projection so softmax runs in exp2 domain
#define QSCALE 0.18033688011112042f

DEV short f2bf(float f) {
  union { float f; unsigned u; } v; v.f = f;
  unsigned r = v.u + 0x7FFFu + ((v.u >> 16) & 1u);
  return (short)(r >> 16);
}

DEV float bf2f(short s) {
  unsigned u = ((unsigned)(unsigned short)s) << 16;
  union { unsigned u; float f; } v; v.u = u;
  return v.f;
}

DEV float exp2_fast(float x) {
#if __has_builtin(__builtin_amdgcn_exp2f)
  return __builtin_amdgcn_exp2f(x);
#else
  return exp2f(x);
#endif
}

DEV float max3f(float a, float b, float c) { return fmaxf(fmaxf(a, b), c); }

DEV unsigned cvt_pk_bf16(float lo, float hi) {
  unsigned r;
  asm("v_cvt_pk_bf16_f32 %0, %1, %2" : "=v"(r) : "v"(lo), "v"(hi));
  return r;
}

// chunk swizzle for LDS staging (both-sides: pre-swizzled source + swizzled read)
DEV int fr(int r) { return (r & 7) ^ (((r >> 3) & 1) << 2); }

// permlane32_swap builtin: ONLY safe with DISTINCT operands (aliased operands
// self-swap and return duplicated values — r6..r9 bisection). Used solely for
// the P fragment pack below, where A != C always.
DEV uint2v pl32swap(unsigned a, unsigned b) {
  return __builtin_amdgcn_permlane32_swap(a, b, false, false);
}
// cross-half (lane ^ 32) combines via ds_bpermute-based __shfl_xor (verified).
DEV float swap_max(float x) { return fmaxf(x, __shfl_xor(x, 32, 64)); }
DEV float swap_add(float x) { return x + __shfl_xor(x, 32, 64); }

DEV void async16(const void* g, void* l) {
  __builtin_amdgcn_global_load_lds((gvoid*)g, (lvoid*)l, 16, 0, 0);
}

// ---------------- input casts ----------------
__global__ __launch_bounds__(256) void cast_qkv(
    const float* __restrict__ q, const float* __restrict__ k,
    const float* __restrict__ v, short* __restrict__ xq,
    short* __restrict__ xk, short* __restrict__ xv) {
  int t = blockIdx.y;
  const float* src = (t == 0) ? q : (t == 1) ? k : v;
  short* dst = (t == 0) ? xq : (t == 1) ? xk : xv;
  long i = (long)(blockIdx.x * 256 + threadIdx.x) * 4;
  float4 f = *(const float4*)(src + i);
  short4v o;
  o[0] = f2bf(f.x); o[1] = f2bf(f.y); o[2] = f2bf(f.z); o[3] = f2bf(f.w);
  *(short4v*)(dst + i) = o;
}

// Wt[w][n][k] = W_w[k][n]  (bf16) — tiled LDS transpose, coalesced both sides
__global__ __launch_bounds__(256) void wtrans(
    const float* __restrict__ wq, const float* __restrict__ wk,
    const float* __restrict__ wv, const float* __restrict__ wo,
    short* __restrict__ wt) {
  __shared__ short T[64 * 72];
  const int tid = threadIdx.x;
  const int n0 = blockIdx.x * 64, k0 = blockIdx.y * 64, w = blockIdx.z;
  const float* W = (w == 0) ? wq : (w == 1) ? wk : (w == 2) ? wv : wo;
  for (int t = 0; t < 4; ++t) {
    int flat = t * 256 + tid;            // 1024 float4 = 64 rows x 16
    int r = flat >> 4, c4 = flat & 15;
    float4 f = *(const float4*)(W + (k0 + r) * 512 + n0 + c4 * 4);
    T[(c4 * 4 + 0) * 72 + r] = f2bf(f.x);
    T[(c4 * 4 + 1) * 72 + r] = f2bf(f.y);
    T[(c4 * 4 + 2) * 72 + r] = f2bf(f.z);
    T[(c4 * 4 + 3) * 72 + r] = f2bf(f.w);
  }
  __syncthreads();
  for (int t = 0; t < 2; ++t) {
    int flat = t * 256 + tid;            // 512 short8 = 64 rows x 8
    int r = flat >> 3, c = flat & 7;
    short8 v = *(const short8*)(T + r * 72 + c * 8);
    *(short8*)(wt + ((long)w << 18) + (n0 + r) * 512 + k0 + c * 8) = v;
  }
}

// ---------------- GEMM main loop (bf16 A/B via async16) -------------------
DEV void gemm_mainloop(const short* __restrict__ A, const short* __restrict__ Bt,
                       short* As, short* Bs, f32x4 acc[4][4]) {
  constexpr int K = 512, BK = 64;
  const int tid = threadIdx.x, lane = tid & 63, w = tid >> 6;
  const int lm = lane & 15, lg = lane >> 4;
  const int wr = w >> 1, wc = w & 1;
  const long bm = (long)blockIdx.y * 128;
  const long bn = (long)blockIdx.x * 128;
  for (int m = 0; m < 4; ++m)
    for (int n = 0; n < 4; ++n) acc[m][n] = {0.f, 0.f, 0.f, 0.f};
  for (int k0 = 0; k0 < K; k0 += BK) {
    __syncthreads();
    for (int t = 0; t < 4; ++t) {
      int flat = t * 256 + tid;
      int row = flat >> 3, c = flat & 7;
      async16(A + (bm + row) * K + k0 + ((c ^ fr(row)) * 8), As + flat * 8);
    }
    for (int t = 0; t < 4; ++t) {
      int flat = t * 256 + tid;
      int row = flat >> 3, c = flat & 7;
      async16(Bt + (bn + row) * K + k0 + ((c ^ fr(row)) * 8), Bs + flat * 8);
    }
    __syncthreads();
    for (int kk = 0; kk < 2; ++kk) {
      short8 a[4], b[4];
      for (int m = 0; m < 4; ++m)
        a[m] = *(const short8*)(As + (wr * 64 + m * 16 + lm) * BK +
                                ((kk * 4 + lg) ^ fr(lm)) * 8);
      for (int n = 0; n < 4; ++n)
        b[n] = *(const short8*)(Bs + (wc * 64 + n * 16 + lm) * BK +
                                ((kk * 4 + lg) ^ fr(lm)) * 8);
      for (int m = 0; m < 4; ++m)
        for (int n = 0; n < 4; ++n)
          acc[m][n] = __builtin_amdgcn_mfma_f32_16x16x32_bf16(a[m], b[n], acc[m][n], 0, 0, 0);
    }
  }
}

template <bool OUT_BF16>
DEV void gemm_epilogue(f32x4 acc[4][4], const float* __restrict__ bias,
                       float scale, void* __restrict__ Yv) {
  constexpr int N = 512;
  const int tid = threadIdx.x, lane = tid & 63, w = tid >> 6;
  const int lm = lane & 15, lg = lane >> 4;
  const int wr = w >> 1, wc = w & 1;
  const long bm = (long)blockIdx.y * 128;
  const long bn = (long)blockIdx.x * 128;
  for (int m = 0; m < 4; ++m)
    for (int n = 0; n < 4; ++n) {
      long row0 = bm + wr * 64 + m * 16 + lg * 4;
      int col = (int)bn + wc * 64 + n * 16 + lm;
      float bb = bias[col];
      for (int j = 0; j < 4; ++j) {
        float val = (acc[m][n][j] + bb) * scale;
        if (OUT_BF16)
          ((short*)Yv)[(row0 + j) * N + col] = f2bf(val);
        else
          ((float*)Yv)[(row0 + j) * N + col] = val;
      }
    }
}

// fused Q/K projections (blockIdx.z selects)
__global__ __launch_bounds__(256) void gemm_proj(
    const short* __restrict__ Xq, const short* __restrict__ Xk,
    const short* __restrict__ Wt, const float* __restrict__ bq,
    const float* __restrict__ bk, short* __restrict__ Qb,
    short* __restrict__ Kb) {
  __shared__ short As[128 * 64];
  __shared__ short Bs[128 * 64];
  int z = blockIdx.z;
  const short* A = (z == 0) ? Xq : Xk;
  const short* Bt = Wt + (long)z * 512 * 512;
  const float* bias = (z == 0) ? bq : bk;
  short* Y = (z == 0) ? Qb : Kb;
  float scale = (z == 0) ? QSCALE : 1.f;
  f32x4 acc[4][4];
  gemm_mainloop(A, Bt, As, Bs, acc);
  gemm_epilogue<true>(acc, bias, scale, Y);
}

// V projection with fused transpose epilogue: writes VT[b][d][s] directly.
// acc tile (128 rows x 128 cols) goes through a swizzled 32KB LDS buffer
// (T[col][rl ^ ((col&7)<<3)], short4 writes / contiguous short8 reads).
__global__ __launch_bounds__(256) void gemm_projV(
    const short* __restrict__ Xv, const short* __restrict__ Wtv,
    const float* __restrict__ bv, short* __restrict__ VT) {
  __shared__ short Sh[128 * 128];  // 32KB: staging (2x 16KB) then transpose
  f32x4 acc[4][4];
  gemm_mainloop(Xv, Wtv, Sh, Sh + 128 * 64, acc);
  __syncthreads();  // K-loop LDS reads done; reuse Sh as transpose buffer
  const int tid = threadIdx.x, lane = tid & 63, w = tid >> 6;
  const int lm = lane & 15, lg = lane >> 4;
  const int wr = w >> 1, wc = w & 1;
  const long bm = (long)blockIdx.y * 128;
  const int bn = (int)blockIdx.x * 128;
  for (int m = 0; m < 4; ++m)
    for (int n = 0; n < 4; ++n) {
      int col = wc * 64 + n * 16 + lm;          // local col 0..127
      int rlb = wr * 64 + m * 16 + lg * 4;      // local row base (mult of 4)
      float bb = bv[bn + col];
      short4v sv;
      for (int j = 0; j < 4; ++j) sv[j] = f2bf(acc[m][n][j] + bb);
      *(short4v*)(Sh + col * 128 + (rlb ^ ((col & 7) << 3))) = sv;
    }
  __syncthreads();
  const int b = (int)(bm >> 12), sbase = (int)(bm & 4095);
  for (int t = 0; t < 8; ++t) {
    int flat = t * 256 + tid;        // 2048 = 128 cols x 16 chunks
    int col = flat >> 4, r8 = flat & 15;
    short8 v = *(const short8*)(Sh + col * 128 + ((r8 ^ (col & 7)) * 8));
    *(short8*)(VT + ((long)b * Dm + bn + col) * Sm + sbase + r8 * 8) = v;
  }
}

__global__ __launch_bounds__(256) void gemm_out(
    const short* __restrict__ A, const short* __restrict__ Bt,
    const float* __restrict__ bias, float* __restrict__ Y) {
  __shared__ short As[128 * 64];
  __shared__ short Bs[128 * 64];
  f32x4 acc[4][4];
  gemm_mainloop(A, Bt, As, Bs, acc);
  gemm_epilogue<false>(acc, bias, 1.f, Y);
}

// ---------------- flash attention, 32x32 MFMA, in-register P ---------------
// 8 waves x 32 q-rows (512 threads); KV-split-4; 4 LDS buffers with one
// barrier per TWO kv-tiles. VALU row-sum keeps VGPR at 64 (occupancy cliff
// at >64 — r18/r19 bisection); ones-MFMA variant rejected (VGPR 72 -> 21%).
template <int NSPLIT>
__global__ __launch_bounds__(512) void attn(
    const short* __restrict__ Qb, const short* __restrict__ Kb,
    const short* __restrict__ VTb, short* __restrict__ Op0,
    short* __restrict__ OpRest, float2* __restrict__ Ml) {
  __shared__ short Ks[4][64 * 64];  // [kv][d], 16B-chunk c at c^fr(kv)
  __shared__ short Vt[4][64 * 64];  // [d][kv], chunk c at c^fr(d)
  const int tid = threadIdx.x, lane = tid & 63, w = tid >> 6;  // w in 0..7
  const int q32 = lane & 31, l5 = lane >> 5;
  const int bh = blockIdx.y, b = bh >> 3, h = bh & 7;
  const int z = blockIdx.z;
  constexpr int KVLEN = Sm / NSPLIT;
  const int kvbase = z * KVLEN;
  const long baseQ = (long)b * Sm * Dm + h * 64;
  const long baseVT = ((long)b * Dm + h * 64) * Sm;
  const int q0w = blockIdx.x * 256 + w * 32;

  // Q fragments (B-operand of 32x32x16): lane holds Q[q0w+q32][ks*16+l5*8 ..+8)
  short8 qf[4];
#pragma unroll
  for (int ks = 0; ks < 4; ++ks)
    qf[ks] = *(const short8*)(Qb + baseQ + (long)(q0w + q32) * Dm + ks * 16 + l5 * 8);

  f32x16 o0, o1;
#pragma unroll
  for (int r = 0; r < 16; ++r) { o0[r] = 0.f; o1[r] = 0.f; }
  float mrun = -1e30f, lrun = 0.f;

  // per-thread staging: 512 threads cover one 64x8-chunk tile exactly
  const int r0 = tid >> 3, c0 = tid & 7;          // row 0..63, chunk 0..7
  const short* gk0 = Kb + baseQ + (long)(kvbase + r0) * Dm + (c0 ^ fr(r0)) * 8;
  const short* gv0 = VTb + baseVT + (long)r0 * Sm + kvbase + (c0 ^ fr(r0)) * 8;
  const int l0 = tid * 8;

  auto stage = [&](int buf) {  // stage current gk/gv tile into buffer, advance
    async16(gk0, &Ks[buf][l0]);
    async16(gv0, &Vt[buf][l0]);
    gk0 += 64 * Dm; gv0 += 64;
  };

  // prologue: stage tiles 0,1 into buffers 0,1
  stage(0);
  stage(1);
  __syncthreads();

  const int cxor = fr(q32);  // same for rows q32 and 32+q32

  auto tile_body = [&](int buf) {
    // QK^T: sc{0,1} = K[kv-half]·Q^T ; lane: q=q32, kv = half*32+(r&3)+8(r>>2)+4*l5
    f32x16 sc0, sc1;
#pragma unroll
    for (int r = 0; r < 16; ++r) { sc0[r] = 0.f; sc1[r] = 0.f; }
    __builtin_amdgcn_s_setprio(1);
#pragma unroll
    for (int ks = 0; ks < 4; ++ks) {
      int cx = (2 * ks + l5) ^ cxor;
      short8 kf0 = *(const short8*)(&Ks[buf][q32 * 64 + cx * 8]);
      short8 kf1 = *(const short8*)(&Ks[buf][(32 + q32) * 64 + cx * 8]);
      sc0 = __builtin_amdgcn_mfma_f32_32x32x16_bf16(kf0, qf[ks], sc0, 0, 0, 0);
      sc1 = __builtin_amdgcn_mfma_f32_32x32x16_bf16(kf1, qf[ks], sc1, 0, 0, 0);
    }
    __builtin_amdgcn_s_setprio(0);

    // lane-local max (cross-half combine deferred into the rare rescale
    // branch; __any spans all 64 lanes so the trigger is exact).
    float t1 = max3f(sc0[0], sc0[1], sc0[2]);
    float t2 = max3f(sc0[3], sc0[4], sc0[5]);
    float t3 = max3f(sc0[6], sc0[7], sc0[8]);
    float t4 = max3f(sc0[9], sc0[10], sc0[11]);
    float t5 = max3f(sc0[12], sc0[13], sc0[14]);
    float ma = max3f(max3f(t1, t2, t3), max3f(t4, t5, sc0[15]), sc1[0]);
    t1 = max3f(sc1[1], sc1[2], sc1[3]);
    t2 = max3f(sc1[4], sc1[5], sc1[6]);
    t3 = max3f(sc1[7], sc1[8], sc1[9]);
    t4 = max3f(sc1[10], sc1[11], sc1[12]);
    t5 = max3f(sc1[13], sc1[14], sc1[15]);
    float tmax_lane = fmaxf(ma, max3f(max3f(t1, t2, t3), t4, t5));

    // defer-max: rescale only when running max grows by > 8 (P bounded by 2^8)
    if (__any(tmax_lane > mrun + 8.f)) {
      float tmax = swap_max(tmax_lane);  // exact row max (rare path only)
      float mi = fmaxf(mrun, tmax);
      float cc = exp2_fast(mrun - mi);
      mrun = mi;
      lrun *= cc;
#pragma unroll
      for (int r = 0; r < 16; ++r) {
        float ccr = __shfl(cc, ((r & 3) + 8 * (r >> 2)) + 4 * l5, 32);
        o0[r] *= ccr;
        o1[r] *= ccr;
      }
    }

    // P = exp2(sc - mrun) in place; tree-structured lane-partial row sum
    float la[4] = {0.f, 0.f, 0.f, 0.f}, lb[4] = {0.f, 0.f, 0.f, 0.f};
#pragma unroll
    for (int r = 0; r < 16; ++r) {
      sc0[r] = exp2_fast(sc0[r] - mrun); la[r & 3] += sc0[r];
      sc1[r] = exp2_fast(sc1[r] - mrun); lb[r & 3] += sc1[r];
    }
    lrun += ((la[0] + la[1]) + (la[2] + la[3])) +
            ((lb[0] + lb[1]) + (lb[2] + lb[3]));

    // PV: per kv-step build pf in-register (cvt_pk + permlane32_swap with
    // DISTINCT operands — verified routing), 2 MFMA
    __builtin_amdgcn_s_setprio(1);
#pragma unroll
    for (int kc = 0; kc < 4; ++kc) {
      const f32x16& sch = (kc < 2) ? sc0 : sc1;
      const int bb = 8 * (kc & 1);
      unsigned A = cvt_pk_bf16(sch[bb + 0], sch[bb + 1]);
      unsigned B = cvt_pk_bf16(sch[bb + 2], sch[bb + 3]);
      unsigned C = cvt_pk_bf16(sch[bb + 4], sch[bb + 5]);
      unsigned D = cvt_pk_bf16(sch[bb + 6], sch[bb + 7]);
      uint2v rac = pl32swap(A, C);  // -> dw0, dw2
      uint2v rbd = pl32swap(B, D);  // -> dw1, dw3
      union { unsigned u[4]; short8 s; } pu;
      pu.u[0] = rac[0]; pu.u[1] = rbd[0]; pu.u[2] = rac[1]; pu.u[3] = rbd[1];
      int cx = (2 * kc + l5) ^ cxor;
      short8 vf0 = *(const short8*)(&Vt[buf][q32 * 64 + cx * 8]);
      short8 vf1 = *(const short8*)(&Vt[buf][(32 + q32) * 64 + cx * 8]);
      o0 = __builtin_amdgcn_mfma_f32_32x32x16_bf16(pu.s, vf0, o0, 0, 0, 0);
      o1 = __builtin_amdgcn_mfma_f32_32x32x16_bf16(pu.s, vf1, o1, 0, 0, 0);
    }
    __builtin_amdgcn_s_setprio(0);
  };

  constexpr int NTILES = KVLEN / 64;  // even for NSPLIT in {2,4}
  for (int it = 0; it < NTILES; it += 2) {
    const int p2 = (it >> 1) & 1;      // current buffer pair
    if (it + 2 < NTILES) {             // prefetch next pair into other buffers
      stage(2 * (1 - p2));
      stage(2 * (1 - p2) + 1);
    }
    tile_body(2 * p2);
    tile_body(2 * p2 + 1);
    __syncthreads();  // next pair resident (vmcnt drained); LDS reads done
  }

  // combine l across lane halves (each lane held half the kv columns)
  lrun = swap_add(lrun);

  // epilogue: store un-normalized partial O (bf16) + per-row (m,l)
  short* Op = (z == 0) ? Op0 : OpRest + (long)(z - 1) * NTe;
#pragma unroll
  for (int r = 0; r < 16; ++r) {
    int q = (r & 3) + 8 * (r >> 2) + 4 * l5;
    long rowoff = baseQ + (long)(q0w + q) * Dm;
    Op[rowoff + q32] = f2bf(o0[r]);
    Op[rowoff + 32 + q32] = f2bf(o1[r]);
  }
  if (l5 == 0) {
    float2 ml; ml.x = mrun; ml.y = lrun;
    Ml[(long)(z * 16 + bh) * Sm + q0w + q32] = ml;
  }
}

// ---------------- merge N KV-split partials (bf16) -> bf16 Ob --------------
template <int NSPLIT>
__global__ __launch_bounds__(256) void mergeN(
    const short* __restrict__ Op0, const short* __restrict__ OpRest,
    const float2* __restrict__ Ml, short* __restrict__ Ob) {
  long idx = (long)blockIdx.x * 256 + threadIdx.x;  // one short8 per thread
  long row = idx >> 6;                               // [B*S) row
  int c8 = (int)(idx & 63);
  int col = c8 * 8;
  int h = col >> 6;
  int b = (int)(row >> 12);
  int s = (int)(row & 4095);
  int bh = b * 8 + h;
  float2 ml[NSPLIT];
  float M = -3e38f;
#pragma unroll
  for (int z = 0; z < NSPLIT; ++z) {
    ml[z] = Ml[(long)(z * 16 + bh) * Sm + s];
    M = fmaxf(M, ml[z].x);
  }
  float wz[NSPLIT], den = 0.f;
#pragma unroll
  for (int z = 0; z < NSPLIT; ++z) {
    wz[z] = exp2_fast(ml[z].x - M);
    den += ml[z].y * wz[z];
  }
  float inv = 1.0f / den;
  long off = row * 512 + col;
  float acc[8];
#pragma unroll
  for (int i = 0; i < 8; ++i) acc[i] = 0.f;
#pragma unroll
  for (int z = 0; z < NSPLIT; ++z) {
    const short* Op = (z == 0) ? Op0 : OpRest + (long)(z - 1) * NTe;
    short8 v = *(const short8*)(Op + off);
#pragma unroll
    for (int i = 0; i < 8; ++i) acc[i] += bf2f(v[i]) * wz[z];
  }
  short8 o;
#pragma unroll
  for (int i = 0; i < 8; ++i) o[i] = f2bf(acc[i] * inv);
  *(short8*)(Ob + off) = o;
}

extern "C" void kernel_launch(void* const* d_in, const int* in_sizes, int n_in,
                              void* d_out, int out_size, void* d_ws, size_t ws_size,
                              hipStream_t stream) {
  const float* query = (const float*)d_in[0];
  const float* key_  = (const float*)d_in[1];
  const float* value = (const float*)d_in[2];
  const float* Wq = (const float*)d_in[3]; const float* bq = (const float*)d_in[4];
  const float* Wk = (const float*)d_in[5]; const float* bk = (const float*)d_in[6];
  const float* Wv = (const float*)d_in[7]; const float* bv = (const float*)d_in[8];
  const float* Wo = (const float*)d_in[9]; const float* bo = (const float*)d_in[10];

  short* Xq = (short*)d_ws;
  short* Xk = Xq + NTe;
  short* Xv = Xk + NTe;
  short* Wt = Xv + NTe;                // [4][512][512] bf16
  short* Qb = Wt + 4 * 512 * 512;
  short* Kb = Qb + NTe;
  short* VT = Kb + NTe;                // V^T [B][512][S] written by gemm_projV
  // partial buffers for KV-split attention (bf16):
  short* Op0 = Xq;                     // overlays Xq (dead after gemm_proj)
  short* OpRest = VT + NTe;            // (NSPLIT-1) bf16 partials after VT
  short* Ob = Xv;                      // overlays Xv (dead after gemm_projV)

  // need for split-4: base shorts + 3*NTe*2 B partials + Ml(4*16*Sm*8 B)
  const size_t base_bytes = (size_t)(6 * NTe + 4 * 512 * 512) * 2;
  const size_t need4 = base_bytes + 3 * (size_t)NTe * 2 + (size_t)4 * 16 * Sm * 8;
  const int nsplit = (ws_size >= need4) ? 4 : 2;
  float2* Ml = (float2*)(OpRest + (size_t)(nsplit - 1) * NTe);

  cast_qkv<<<dim3(4096, 3), 256, 0, stream>>>(query, key_, value, Xq, Xk, Xv);
  wtrans<<<dim3(8, 8, 4), 256, 0, stream>>>(Wq, Wk, Wv, Wo, Wt);

  gemm_proj<<<dim3(4, 64, 2), 256, 0, stream>>>(Xq, Xk, Wt, bq, bk, Qb, Kb);
  gemm_projV<<<dim3(4, 64), 256, 0, stream>>>(Xv, Wt + 2L * 512 * 512, bv, VT);

  if (nsplit == 4) {
    attn<4><<<dim3(Sm / 256, 2 * Hh, 4), 512, 0, stream>>>(Qb, Kb, VT, Op0,
                                                           OpRest, Ml);
    mergeN<4><<<dim3((2 * Sm * 512 / 8) / 256), 256, 0, stream>>>(Op0, OpRest,
                                                                  Ml, Ob);
  } else {
    attn<2><<<dim3(Sm / 256, 2 * Hh, 2), 512, 0, stream>>>(Qb, Kb, VT, Op0,
                                                           OpRest, Ml);
    mergeN<2><<<dim3((2 * Sm * 512 / 8) / 256), 256, 0, stream>>>(Op0, OpRest,
                                                                  Ml, Ob);
  }

  gemm_out<<<dim3(4, 64), 256, 0, stream>>>(Ob, Wt + 3L * 512 * 512, bo,
                                            (float*)d_out);
}

// Round 22
// 157.058 us; speedup vs baseline: 1.0268x; 1.0268x over previous
//
#include <hip/hip_runtime.h>

typedef short short8 __attribute__((ext_vector_type(8)));
typedef short short4v __attribute__((ext_vector_type(4)));
typedef float f32x4 __attribute__((ext_vector_type(4)));
typedef float f32x16 __attribute__((ext_vector_type(16)));
typedef unsigned uint2v __attribute__((ext_vector_type(2)));

typedef __attribute__((address_space(1))) void gvoid;
typedef __attribute__((address_space(3))) void lvoid;

#define DEV static __device__ __forceinline__

constexpr int Dm = 512;   // model dim
constexpr int Sm = 4096;  // seq len
constexpr int Hh = 8;     // heads
constexpr long NTe = (long)2 * Sm * Dm;  // elements per [B,S,D] tensor

// 0.125 (=1/sqrt(64)) * log2(e): folded into Q projection so softmax runs in exp2 domain
#define QSCALE 0.18033688011112042f

DEV short f2bf(float f) {
  union { float f; unsigned u; } v; v.f = f;
  unsigned r = v.u + 0x7FFFu + ((v.u >> 16) & 1u);
  return (short)(r >> 16);
}

DEV float bf2f(short s) {
  unsigned u = ((unsigned)(unsigned short)s) << 16;
  union { unsigned u; float f; } v; v.u = u;
  return v.f;
}

DEV float exp2_fast(float x) {
#if __has_builtin(__builtin_amdgcn_exp2f)
  return __builtin_amdgcn_exp2f(x);
#else
  return exp2f(x);
#endif
}

DEV float max3f(float a, float b, float c) { return fmaxf(fmaxf(a, b), c); }

DEV unsigned cvt_pk_bf16(float lo, float hi) {
  unsigned r;
  asm("v_cvt_pk_bf16_f32 %0, %1, %2" : "=v"(r) : "v"(lo), "v"(hi));
  return r;
}

// chunk swizzle for LDS staging (both-sides: pre-swizzled source + swizzled read)
DEV int fr(int r) { return (r & 7) ^ (((r >> 3) & 1) << 2); }

// permlane32_swap builtin: ONLY safe with DISTINCT operands (aliased operands
// self-swap and return duplicated values — r6..r9 bisection). Used solely for
// the P fragment pack below, where A != C always.
DEV uint2v pl32swap(unsigned a, unsigned b) {
  return __builtin_amdgcn_permlane32_swap(a, b, false, false);
}
// cross-half (lane ^ 32) combines via ds_bpermute-based __shfl_xor (verified).
DEV float swap_max(float x) { return fmaxf(x, __shfl_xor(x, 32, 64)); }
DEV float swap_add(float x) { return x + __shfl_xor(x, 32, 64); }

DEV void async16(const void* g, void* l) {
  __builtin_amdgcn_global_load_lds((gvoid*)g, (lvoid*)l, 16, 0, 0);
}

// ---------------- input casts ----------------
__global__ __launch_bounds__(256) void cast_qkv(
    const float* __restrict__ q, const float* __restrict__ k,
    const float* __restrict__ v, short* __restrict__ xq,
    short* __restrict__ xk, short* __restrict__ xv) {
  int t = blockIdx.y;
  const float* src = (t == 0) ? q : (t == 1) ? k : v;
  short* dst = (t == 0) ? xq : (t == 1) ? xk : xv;
  long i = (long)(blockIdx.x * 256 + threadIdx.x) * 4;
  float4 f = *(const float4*)(src + i);
  short4v o;
  o[0] = f2bf(f.x); o[1] = f2bf(f.y); o[2] = f2bf(f.z); o[3] = f2bf(f.w);
  *(short4v*)(dst + i) = o;
}

// Wt[w][n][k] = W_w[k][n]  (bf16) — tiled LDS transpose, coalesced both sides
__global__ __launch_bounds__(256) void wtrans(
    const float* __restrict__ wq, const float* __restrict__ wk,
    const float* __restrict__ wv, const float* __restrict__ wo,
    short* __restrict__ wt) {
  __shared__ short T[64 * 72];
  const int tid = threadIdx.x;
  const int n0 = blockIdx.x * 64, k0 = blockIdx.y * 64, w = blockIdx.z;
  const float* W = (w == 0) ? wq : (w == 1) ? wk : (w == 2) ? wv : wo;
  for (int t = 0; t < 4; ++t) {
    int flat = t * 256 + tid;            // 1024 float4 = 64 rows x 16
    int r = flat >> 4, c4 = flat & 15;
    float4 f = *(const float4*)(W + (k0 + r) * 512 + n0 + c4 * 4);
    T[(c4 * 4 + 0) * 72 + r] = f2bf(f.x);
    T[(c4 * 4 + 1) * 72 + r] = f2bf(f.y);
    T[(c4 * 4 + 2) * 72 + r] = f2bf(f.z);
    T[(c4 * 4 + 3) * 72 + r] = f2bf(f.w);
  }
  __syncthreads();
  for (int t = 0; t < 2; ++t) {
    int flat = t * 256 + tid;            // 512 short8 = 64 rows x 8
    int r = flat >> 3, c = flat & 7;
    short8 v = *(const short8*)(T + r * 72 + c * 8);
    *(short8*)(wt + ((long)w << 18) + (n0 + r) * 512 + k0 + c * 8) = v;
  }
}

// ---------------- V transpose: V[b*S+s][d] -> VT[b][d][s] ----------------
__global__ __launch_bounds__(256) void vtrans(
    const short* __restrict__ V, short* __restrict__ VT) {
  __shared__ short T[64 * 72];
  const int tid = threadIdx.x;
  const int s0 = blockIdx.x * 64, d0 = blockIdx.y * 64, b = blockIdx.z;
  for (int t = 0; t < 2; ++t) {
    int flat = t * 256 + tid;
    int sl = flat >> 3, c = flat & 7;
    short8 v = *(const short8*)(V + ((long)b * Sm + s0 + sl) * Dm + d0 + c * 8);
    for (int j = 0; j < 8; ++j) T[(c * 8 + j) * 72 + sl] = v[j];
  }
  __syncthreads();
  for (int t = 0; t < 2; ++t) {
    int flat = t * 256 + tid;
    int dl = flat >> 3, c = flat & 7;
    short8 v = *(const short8*)(T + dl * 72 + c * 8);
    *(short8*)(VT + ((long)b * Dm + d0 + dl) * Sm + s0 + c * 8) = v;
  }
}

// ---------------- GEMM core (bf16 A/B via async16): Y = A*Bt + bias --------
template <bool OUT_BF16>
DEV void gemm_body(const short* __restrict__ A, const short* __restrict__ Bt,
                   const float* __restrict__ bias, float scale,
                   void* __restrict__ Yv, short* As, short* Bs) {
  constexpr int K = 512, N = 512, BK = 64;
  const int tid = threadIdx.x, lane = tid & 63, w = tid >> 6;
  const int lm = lane & 15, lg = lane >> 4;
  const int wr = w >> 1, wc = w & 1;
  const long bm = (long)blockIdx.y * 128;
  const long bn = (long)blockIdx.x * 128;
  f32x4 zero = {0.f, 0.f, 0.f, 0.f};
  f32x4 acc[4][4];
  for (int m = 0; m < 4; ++m)
    for (int n = 0; n < 4; ++n) acc[m][n] = zero;
  for (int k0 = 0; k0 < K; k0 += BK) {
    __syncthreads();
    for (int t = 0; t < 4; ++t) {
      int flat = t * 256 + tid;
      int row = flat >> 3, c = flat & 7;
      async16(A + (bm + row) * K + k0 + ((c ^ fr(row)) * 8), As + flat * 8);
    }
    for (int t = 0; t < 4; ++t) {
      int flat = t * 256 + tid;
      int row = flat >> 3, c = flat & 7;
      async16(Bt + (bn + row) * K + k0 + ((c ^ fr(row)) * 8), Bs + flat * 8);
    }
    __syncthreads();
    for (int kk = 0; kk < 2; ++kk) {
      short8 a[4], b[4];
      for (int m = 0; m < 4; ++m)
        a[m] = *(const short8*)(As + (wr * 64 + m * 16 + lm) * BK +
                                ((kk * 4 + lg) ^ fr(lm)) * 8);
      for (int n = 0; n < 4; ++n)
        b[n] = *(const short8*)(Bs + (wc * 64 + n * 16 + lm) * BK +
                                ((kk * 4 + lg) ^ fr(lm)) * 8);
      for (int m = 0; m < 4; ++m)
        for (int n = 0; n < 4; ++n)
          acc[m][n] = __builtin_amdgcn_mfma_f32_16x16x32_bf16(a[m], b[n], acc[m][n], 0, 0, 0);
    }
  }
  for (int m = 0; m < 4; ++m)
    for (int n = 0; n < 4; ++n) {
      long row0 = bm + wr * 64 + m * 16 + lg * 4;
      int col = (int)bn + wc * 64 + n * 16 + lm;
      float bb = bias[col];
      for (int j = 0; j < 4; ++j) {
        float val = (acc[m][n][j] + bb) * scale;
        if (OUT_BF16)
          ((short*)Yv)[(row0 + j) * N + col] = f2bf(val);
        else
          ((float*)Yv)[(row0 + j) * N + col] = val;
      }
    }
}

// fused Q/K/V projections (blockIdx.z selects)
__global__ __launch_bounds__(256) void gemm_proj(
    const short* __restrict__ Xq, const short* __restrict__ Xk,
    const short* __restrict__ Xv, const short* __restrict__ Wt,
    const float* __restrict__ bq, const float* __restrict__ bk,
    const float* __restrict__ bv, short* __restrict__ Qb,
    short* __restrict__ Kb, short* __restrict__ Vb) {
  __shared__ short As[128 * 64];
  __shared__ short Bs[128 * 64];
  int z = blockIdx.z;
  const short* A = (z == 0) ? Xq : (z == 1) ? Xk : Xv;
  const short* Bt = Wt + (long)z * 512 * 512;
  const float* bias = (z == 0) ? bq : (z == 1) ? bk : bv;
  short* Y = (z == 0) ? Qb : (z == 1) ? Kb : Vb;
  float scale = (z == 0) ? QSCALE : 1.f;
  gemm_body<true>(A, Bt, bias, scale, Y, As, Bs);
}

__global__ __launch_bounds__(256) void gemm_out(
    const short* __restrict__ A, const short* __restrict__ Bt,
    const float* __restrict__ bias, float* __restrict__ Y) {
  __shared__ short As[128 * 64];
  __shared__ short Bs[128 * 64];
  gemm_body<false>(A, Bt, bias, 1.f, Y, As, Bs);
}

// ---------------- flash attention, 32x32 MFMA, in-register P ---------------
// 8 waves x 32 q-rows (512 threads); KV-split-4; 4 LDS buffers with one
// barrier per TWO kv-tiles. VALU row-sum keeps VGPR at 64 (occupancy cliff
// at >64 — r18/r19 bisection); ones-MFMA variant rejected (VGPR 72 -> 21%).
template <int NSPLIT>
__global__ __launch_bounds__(512) void attn(
    const short* __restrict__ Qb, const short* __restrict__ Kb,
    const short* __restrict__ VTb, short* __restrict__ Op0,
    short* __restrict__ OpRest, float2* __restrict__ Ml) {
  __shared__ short Ks[4][64 * 64];  // [kv][d], 16B-chunk c at c^fr(kv)
  __shared__ short Vt[4][64 * 64];  // [d][kv], chunk c at c^fr(d)
  const int tid = threadIdx.x, lane = tid & 63, w = tid >> 6;  // w in 0..7
  const int q32 = lane & 31, l5 = lane >> 5;
  const int bh = blockIdx.y, b = bh >> 3, h = bh & 7;
  const int z = blockIdx.z;
  constexpr int KVLEN = Sm / NSPLIT;
  const int kvbase = z * KVLEN;
  const long baseQ = (long)b * Sm * Dm + h * 64;
  const long baseVT = ((long)b * Dm + h * 64) * Sm;
  const int q0w = blockIdx.x * 256 + w * 32;

  // Q fragments (B-operand of 32x32x16): lane holds Q[q0w+q32][ks*16+l5*8 ..+8)
  short8 qf[4];
#pragma unroll
  for (int ks = 0; ks < 4; ++ks)
    qf[ks] = *(const short8*)(Qb + baseQ + (long)(q0w + q32) * Dm + ks * 16 + l5 * 8);

  f32x16 o0, o1;
#pragma unroll
  for (int r = 0; r < 16; ++r) { o0[r] = 0.f; o1[r] = 0.f; }
  float mrun = -1e30f, lrun = 0.f;

  // per-thread staging: 512 threads cover one 64x8-chunk tile exactly
  const int r0 = tid >> 3, c0 = tid & 7;          // row 0..63, chunk 0..7
  const short* gk0 = Kb + baseQ + (long)(kvbase + r0) * Dm + (c0 ^ fr(r0)) * 8;
  const short* gv0 = VTb + baseVT + (long)r0 * Sm + kvbase + (c0 ^ fr(r0)) * 8;
  const int l0 = tid * 8;

  auto stage = [&](int buf) {  // stage current gk/gv tile into buffer, advance
    async16(gk0, &Ks[buf][l0]);
    async16(gv0, &Vt[buf][l0]);
    gk0 += 64 * Dm; gv0 += 64;
  };

  // prologue: stage tiles 0,1 into buffers 0,1
  stage(0);
  stage(1);
  __syncthreads();

  const int cxor = fr(q32);  // same for rows q32 and 32+q32

  auto tile_body = [&](int buf) {
    // QK^T: sc{0,1} = K[kv-half]·Q^T ; lane: q=q32, kv = half*32+(r&3)+8(r>>2)+4*l5
    f32x16 sc0, sc1;
#pragma unroll
    for (int r = 0; r < 16; ++r) { sc0[r] = 0.f; sc1[r] = 0.f; }
    __builtin_amdgcn_s_setprio(1);
#pragma unroll
    for (int ks = 0; ks < 4; ++ks) {
      int cx = (2 * ks + l5) ^ cxor;
      short8 kf0 = *(const short8*)(&Ks[buf][q32 * 64 + cx * 8]);
      short8 kf1 = *(const short8*)(&Ks[buf][(32 + q32) * 64 + cx * 8]);
      sc0 = __builtin_amdgcn_mfma_f32_32x32x16_bf16(kf0, qf[ks], sc0, 0, 0, 0);
      sc1 = __builtin_amdgcn_mfma_f32_32x32x16_bf16(kf1, qf[ks], sc1, 0, 0, 0);
    }
    __builtin_amdgcn_s_setprio(0);

    // lane-local max (cross-half combine deferred into the rare rescale
    // branch; __any spans all 64 lanes so the trigger is exact).
    float t1 = max3f(sc0[0], sc0[1], sc0[2]);
    float t2 = max3f(sc0[3], sc0[4], sc0[5]);
    float t3 = max3f(sc0[6], sc0[7], sc0[8]);
    float t4 = max3f(sc0[9], sc0[10], sc0[11]);
    float t5 = max3f(sc0[12], sc0[13], sc0[14]);
    float ma = max3f(max3f(t1, t2, t3), max3f(t4, t5, sc0[15]), sc1[0]);
    t1 = max3f(sc1[1], sc1[2], sc1[3]);
    t2 = max3f(sc1[4], sc1[5], sc1[6]);
    t3 = max3f(sc1[7], sc1[8], sc1[9]);
    t4 = max3f(sc1[10], sc1[11], sc1[12]);
    t5 = max3f(sc1[13], sc1[14], sc1[15]);
    float tmax_lane = fmaxf(ma, max3f(max3f(t1, t2, t3), t4, t5));

    // defer-max: rescale only when running max grows by > 8 (P bounded by 2^8)
    if (__any(tmax_lane > mrun + 8.f)) {
      float tmax = swap_max(tmax_lane);  // exact row max (rare path only)
      float mi = fmaxf(mrun, tmax);
      float cc = exp2_fast(mrun - mi);
      mrun = mi;
      lrun *= cc;
#pragma unroll
      for (int r = 0; r < 16; ++r) {
        float ccr = __shfl(cc, ((r & 3) + 8 * (r >> 2)) + 4 * l5, 32);
        o0[r] *= ccr;
        o1[r] *= ccr;
      }
    }

    // P = exp2(sc - mrun) in place; tree-structured lane-partial row sum
    float la[4] = {0.f, 0.f, 0.f, 0.f}, lb[4] = {0.f, 0.f, 0.f, 0.f};
#pragma unroll
    for (int r = 0; r < 16; ++r) {
      sc0[r] = exp2_fast(sc0[r] - mrun); la[r & 3] += sc0[r];
      sc1[r] = exp2_fast(sc1[r] - mrun); lb[r & 3] += sc1[r];
    }
    lrun += ((la[0] + la[1]) + (la[2] + la[3])) +
            ((lb[0] + lb[1]) + (lb[2] + lb[3]));

    // PV: per kv-step build pf in-register (cvt_pk + permlane32_swap with
    // DISTINCT operands — verified routing), 2 MFMA
    __builtin_amdgcn_s_setprio(1);
#pragma unroll
    for (int kc = 0; kc < 4; ++kc) {
      const f32x16& sch = (kc < 2) ? sc0 : sc1;
      const int bb = 8 * (kc & 1);
      unsigned A = cvt_pk_bf16(sch[bb + 0], sch[bb + 1]);
      unsigned B = cvt_pk_bf16(sch[bb + 2], sch[bb + 3]);
      unsigned C = cvt_pk_bf16(sch[bb + 4], sch[bb + 5]);
      unsigned D = cvt_pk_bf16(sch[bb + 6], sch[bb + 7]);
      uint2v rac = pl32swap(A, C);  // -> dw0, dw2
      uint2v rbd = pl32swap(B, D);  // -> dw1, dw3
      union { unsigned u[4]; short8 s; } pu;
      pu.u[0] = rac[0]; pu.u[1] = rbd[0]; pu.u[2] = rac[1]; pu.u[3] = rbd[1];
      int cx = (2 * kc + l5) ^ cxor;
      short8 vf0 = *(const short8*)(&Vt[buf][q32 * 64 + cx * 8]);
      short8 vf1 = *(const short8*)(&Vt[buf][(32 + q32) * 64 + cx * 8]);
      o0 = __builtin_amdgcn_mfma_f32_32x32x16_bf16(pu.s, vf0, o0, 0, 0, 0);
      o1 = __builtin_amdgcn_mfma_f32_32x32x16_bf16(pu.s, vf1, o1, 0, 0, 0);
    }
    __builtin_amdgcn_s_setprio(0);
  };

  constexpr int NTILES = KVLEN / 64;  // even for NSPLIT in {2,4}
  for (int it = 0; it < NTILES; it += 2) {
    const int p2 = (it >> 1) & 1;      // current buffer pair
    if (it + 2 < NTILES) {             // prefetch next pair into other buffers
      stage(2 * (1 - p2));
      stage(2 * (1 - p2) + 1);
    }
    tile_body(2 * p2);
    tile_body(2 * p2 + 1);
    __syncthreads();  // next pair resident (vmcnt drained); LDS reads done
  }

  // combine l across lane halves (each lane held half the kv columns)
  lrun = swap_add(lrun);

  // epilogue: store un-normalized partial O (bf16) + per-row (m,l)
  short* Op = (z == 0) ? Op0 : OpRest + (long)(z - 1) * NTe;
#pragma unroll
  for (int r = 0; r < 16; ++r) {
    int q = (r & 3) + 8 * (r >> 2) + 4 * l5;
    long rowoff = baseQ + (long)(q0w + q) * Dm;
    Op[rowoff + q32] = f2bf(o0[r]);
    Op[rowoff + 32 + q32] = f2bf(o1[r]);
  }
  if (l5 == 0) {
    float2 ml; ml.x = mrun; ml.y = lrun;
    Ml[(long)(z * 16 + bh) * Sm + q0w + q32] = ml;
  }
}

// ---------------- merge N KV-split partials (bf16) -> bf16 Ob --------------
template <int NSPLIT>
__global__ __launch_bounds__(256) void mergeN(
    const short* __restrict__ Op0, const short* __restrict__ OpRest,
    const float2* __restrict__ Ml, short* __restrict__ Ob) {
  long idx = (long)blockIdx.x * 256 + threadIdx.x;  // one short8 per thread
  long row = idx >> 6;                               // [B*S) row
  int c8 = (int)(idx & 63);
  int col = c8 * 8;
  int h = col >> 6;
  int b = (int)(row >> 12);
  int s = (int)(row & 4095);
  int bh = b * 8 + h;
  float2 ml[NSPLIT];
  float M = -3e38f;
#pragma unroll
  for (int z = 0; z < NSPLIT; ++z) {
    ml[z] = Ml[(long)(z * 16 + bh) * Sm + s];
    M = fmaxf(M, ml[z].x);
  }
  float wz[NSPLIT], den = 0.f;
#pragma unroll
  for (int z = 0; z < NSPLIT; ++z) {
    wz[z] = exp2_fast(ml[z].x - M);
    den += ml[z].y * wz[z];
  }
  float inv = 1.0f / den;
  long off = row * 512 + col;
  float acc[8];
#pragma unroll
  for (int i = 0; i < 8; ++i) acc[i] = 0.f;
#pragma unroll
  for (int z = 0; z < NSPLIT; ++z) {
    const short* Op = (z == 0) ? Op0 : OpRest + (long)(z - 1) * NTe;
    short8 v = *(const short8*)(Op + off);
#pragma unroll
    for (int i = 0; i < 8; ++i) acc[i] += bf2f(v[i]) * wz[z];
  }
  short8 o;
#pragma unroll
  for (int i = 0; i < 8; ++i) o[i] = f2bf(acc[i] * inv);
  *(short8*)(Ob + off) = o;
}

extern "C" void kernel_launch(void* const* d_in, const int* in_sizes, int n_in,
                              void* d_out, int out_size, void* d_ws, size_t ws_size,
                              hipStream_t stream) {
  const float* query = (const float*)d_in[0];
  const float* key_  = (const float*)d_in[1];
  const float* value = (const float*)d_in[2];
  const float* Wq = (const float*)d_in[3]; const float* bq = (const float*)d_in[4];
  const float* Wk = (const float*)d_in[5]; const float* bk = (const float*)d_in[6];
  const float* Wv = (const float*)d_in[7]; const float* bv = (const float*)d_in[8];
  const float* Wo = (const float*)d_in[9]; const float* bo = (const float*)d_in[10];

  short* Xq = (short*)d_ws;
  short* Xk = Xq + NTe;
  short* Xv = Xk + NTe;
  short* Wt = Xv + NTe;                // [4][512][512] bf16
  short* Qb = Wt + 4 * 512 * 512;
  short* Kb = Qb + NTe;
  short* Vb = Kb + NTe;
  short* VT = Xv;                      // reuse Xv (dead after V projection)
  // partial buffers for KV-split attention (bf16):
  short* Op0 = Xq;                     // overlays Xq (dead after gemm_proj)
  short* OpRest = Vb + NTe;            // (NSPLIT-1) bf16 partials after Vb
  short* Ob = Vb;                      // overlays Vb (dead after vtrans)

  // need for split-4: base shorts + 3*NTe*2 B partials + Ml(4*16*Sm*8 B)
  const size_t base_bytes = (size_t)(6 * NTe + 4 * 512 * 512) * 2;
  const size_t need4 = base_bytes + 3 * (size_t)NTe * 2 + (size_t)4 * 16 * Sm * 8;
  const int nsplit = (ws_size >= need4) ? 4 : 2;
  float2* Ml = (float2*)(OpRest + (size_t)(nsplit - 1) * NTe);

  cast_qkv<<<dim3(4096, 3), 256, 0, stream>>>(query, key_, value, Xq, Xk, Xv);
  wtrans<<<dim3(8, 8, 4), 256, 0, stream>>>(Wq, Wk, Wv, Wo, Wt);

  gemm_proj<<<dim3(4, 64, 3), 256, 0, stream>>>(Xq, Xk, Xv, Wt, bq, bk, bv,
                                                Qb, Kb, Vb);

  vtrans<<<dim3(Sm / 64, Dm / 64, 2), 256, 0, stream>>>(Vb, VT);

  if (nsplit == 4) {
    attn<4><<<dim3(Sm / 256, 2 * Hh, 4), 512, 0, stream>>>(Qb, Kb, VT, Op0,
                                                           OpRest, Ml);
    mergeN<4><<<dim3((2 * Sm * 512 / 8) / 256), 256, 0, stream>>>(Op0, OpRest,
                                                                  Ml, Ob);
  } else {
    attn<2><<<dim3(Sm / 256, 2 * Hh, 2), 512, 0, stream>>>(Qb, Kb, VT, Op0,
                                                           OpRest, Ml);
    mergeN<2><<<dim3((2 * Sm * 512 / 8) / 256), 256, 0, stream>>>(Op0, OpRest,
                                                                  Ml, Ob);
  }

  gemm_out<<<dim3(4, 64), 256, 0, stream>>>(Ob, Wt + 3L * 512 * 512, bo,
                                            (float*)d_out);
}